// Round 1
// baseline (250.475 us; speedup 1.0000x reference)
//
#include <hip/hip_runtime.h>
#include <hip/hip_bf16.h>
#include <cstdint>

using f32x4   = __attribute__((ext_vector_type(4))) float;
using bf16x8_t = __attribute__((ext_vector_type(8))) __bf16;

// Problem dims
#define BATCH   128
#define NPATCH  196
#define NPAD    224
#define DDIM    768
#define WCON    32
#define NCOLS   4096   // BATCH*WCON

// ws layout (bytes)
#define P_BYTES   (128ull*224*768*2)   // padded bf16 patches
#define C_BYTES   (4096ull*768*2)      // bf16 concepts
#define F_BYTES   (128ull*768*4)       // f32 normalized cls rows
#define MAX_BYTES (128ull*4096*4)
#define P_OFF     0ull
#define C_OFF     (P_OFF + P_BYTES)
#define IMGN_OFF  (C_OFF + C_BYTES)
#define TXTN_OFF  (IMGN_OFF + F_BYTES)
#define MAX_OFF   (TXTN_OFF + F_BYTES)
#define ACC_OFF   (MAX_OFF + MAX_BYTES)
#define WS_NEED   (ACC_OFF + 256ull)

__device__ __forceinline__ ushort f2bf(float f) {
  unsigned u = __float_as_uint(f);
  unsigned r = (u + 0x7fffu + ((u >> 16) & 1u)) >> 16;
  return (ushort)r;
}

__device__ __forceinline__ void async_cp16(void* lds, const void* g) {
  __builtin_amdgcn_global_load_lds(
      (const __attribute__((address_space(1))) unsigned int*)g,
      (__attribute__((address_space(3))) unsigned int*)lds, 16, 0, 0);
}

__device__ __forceinline__ float neg_log_sigmoid(float x) {
  // returns -log_sigmoid(x), numerically stable
  return (x > 0.f) ? log1pf(expf(-x)) : (log1pf(expf(x)) - x);
}

// ---------------- normalization kernels ----------------

// one row of 768 f32 per block, 192 threads (3 waves), f32 out
__global__ void norm_f32_kernel(const float* __restrict__ in, float* __restrict__ out) {
  int row = blockIdx.x;
  int t = threadIdx.x; // 0..191
  const float4* ir = (const float4*)(in + (size_t)row * DDIM);
  float4 v = ir[t];
  float ss = v.x*v.x + v.y*v.y + v.z*v.z + v.w*v.w;
  __shared__ float sb[3];
  #pragma unroll
  for (int o = 32; o; o >>= 1) ss += __shfl_down(ss, o);
  if ((t & 63) == 0) sb[t >> 6] = ss;
  __syncthreads();
  float tot = sb[0] + sb[1] + sb[2];
  float scale = 1.0f / fmaxf(sqrtf(tot), 1e-12f);
  float4 o4 = make_float4(v.x*scale, v.y*scale, v.z*scale, v.w*scale);
  ((float4*)(out + (size_t)row * DDIM))[t] = o4;
}

// one row per block; rows r >= rin are zero padding
__global__ void norm_bf16_kernel(const float* __restrict__ in, ushort* __restrict__ out,
                                 int rin, int rout) {
  int bid = blockIdx.x;
  int img = bid / rout;
  int r = bid - img * rout;
  int t = threadIdx.x; // 0..191
  ushort4* orow = (ushort4*)(out + (size_t)bid * DDIM);
  if (r >= rin) { orow[t] = make_ushort4(0,0,0,0); return; }
  const float4* ir = (const float4*)(in + ((size_t)img * rin + r) * DDIM);
  float4 v = ir[t];
  float ss = v.x*v.x + v.y*v.y + v.z*v.z + v.w*v.w;
  __shared__ float sb[3];
  #pragma unroll
  for (int o = 32; o; o >>= 1) ss += __shfl_down(ss, o);
  if ((t & 63) == 0) sb[t >> 6] = ss;
  __syncthreads();
  float tot = sb[0] + sb[1] + sb[2];
  float scale = 1.0f / fmaxf(sqrtf(tot), 1e-12f);
  orow[t] = make_ushort4(f2bf(v.x*scale), f2bf(v.y*scale), f2bf(v.z*scale), f2bf(v.w*scale));
}

// ---------------- RC GEMM + column max ----------------
// Block: m = bid>>5, col chunk bv = bid&31 (128 concept cols).
// Tile 224x128, K=768 in 24 steps of 32. 4 waves (2x2), wave tile 112x64.
__global__ __launch_bounds__(256, 2)
void rc_gemm_max_kernel(const ushort* __restrict__ patches,
                        const ushort* __restrict__ concepts,
                        float* __restrict__ Max) {
  __shared__ __align__(16) ushort As[224*32];
  __shared__ __align__(16) ushort Bs[128*32];
  __shared__ float colmax[2][128];

  int bid = blockIdx.x;
  int bm = bid >> 5;
  int bv = bid & 31;
  int tid = threadIdx.x;
  int lane = tid & 63;
  int wid = tid >> 6;
  int wm = wid >> 1, wn = wid & 1;

  const ushort* Ab = patches  + (size_t)bm * (NPAD * DDIM);
  const ushort* Bb = concepts + (size_t)bv * (128 * DDIM);

  // swizzled LDS read offsets: byte = row*64 + (q ^ ((row>>1)&3))*16
  int a_off[7], b_off[4];
  #pragma unroll
  for (int i = 0; i < 7; ++i) {
    int row = wm*112 + i*16 + (lane & 15);
    int q = (lane >> 4) ^ ((row >> 1) & 3);
    a_off[i] = row*64 + q*16;
  }
  #pragma unroll
  for (int j = 0; j < 4; ++j) {
    int col = wn*64 + j*16 + (lane & 15);
    int q = (lane >> 4) ^ ((col >> 1) & 3);
    b_off[j] = col*64 + q*16;
  }

  f32x4 acc[7][4];
  #pragma unroll
  for (int i = 0; i < 7; ++i)
    #pragma unroll
    for (int j = 0; j < 4; ++j) {
      f32x4 z = {0.f, 0.f, 0.f, 0.f};
      acc[i][j] = z;
    }

  for (int k0 = 0; k0 < DDIM; k0 += 32) {
    // stage A: 896 chunks of 16B, LDS dest linear, global source pre-swizzled
    #pragma unroll
    for (int itr = 0; itr < 3; ++itr) {
      int d = tid + itr*256;
      int r = d >> 2;
      int q = (d & 3) ^ ((r >> 1) & 3);
      async_cp16((char*)As + d*16, Ab + (size_t)r*DDIM + k0 + q*8);
    }
    if (tid < 128) {
      int d = tid + 768;
      int r = d >> 2;
      int q = (d & 3) ^ ((r >> 1) & 3);
      async_cp16((char*)As + d*16, Ab + (size_t)r*DDIM + k0 + q*8);
    }
    // stage B: 512 chunks
    #pragma unroll
    for (int itr = 0; itr < 2; ++itr) {
      int d = tid + itr*256;
      int c = d >> 2;
      int q = (d & 3) ^ ((c >> 1) & 3);
      async_cp16((char*)Bs + d*16, Bb + (size_t)c*DDIM + k0 + q*8);
    }
    __syncthreads();   // drains vmcnt before LDS reads

    bf16x8_t a[7], b[4];
    #pragma unroll
    for (int i = 0; i < 7; ++i)
      a[i] = *(const bf16x8_t*)((const char*)As + a_off[i]);
    #pragma unroll
    for (int j = 0; j < 4; ++j)
      b[j] = *(const bf16x8_t*)((const char*)Bs + b_off[j]);
    #pragma unroll
    for (int i = 0; i < 7; ++i)
      #pragma unroll
      for (int j = 0; j < 4; ++j)
        acc[i][j] = __builtin_amdgcn_mfma_f32_16x16x32_bf16(a[i], b[j], acc[i][j], 0, 0, 0);
    __syncthreads();
  }

  // epilogue: masked column max. D layout: col = lane&15, row = (lane>>4)*4 + e
  float cmax[4] = {-1e30f, -1e30f, -1e30f, -1e30f};
  int rb = wm*112 + (lane >> 4)*4;
  #pragma unroll
  for (int i = 0; i < 7; ++i) {
    #pragma unroll
    for (int e = 0; e < 4; ++e) {
      if (rb + i*16 + e < NPATCH) {
        #pragma unroll
        for (int j = 0; j < 4; ++j) cmax[j] = fmaxf(cmax[j], acc[i][j][e]);
      }
    }
  }
  #pragma unroll
  for (int j = 0; j < 4; ++j) {
    cmax[j] = fmaxf(cmax[j], __shfl_xor(cmax[j], 16));
    cmax[j] = fmaxf(cmax[j], __shfl_xor(cmax[j], 32));
  }
  if (lane < 16) {
    #pragma unroll
    for (int j = 0; j < 4; ++j) colmax[wm][wn*64 + j*16 + lane] = cmax[j];
  }
  __syncthreads();
  if (tid < 128) {
    float mx = fmaxf(colmax[0][tid], colmax[1][tid]);
    Max[(size_t)bm * NCOLS + (size_t)bv*128 + tid] = mx;
  }
}

// ---------------- losses ----------------

__global__ void it_loss_kernel(const float* __restrict__ imgn, const float* __restrict__ txtn,
                               const float* __restrict__ sc, const float* __restrict__ bi,
                               float* __restrict__ acc) {
  int m = blockIdx.x;
  int c = threadIdx.x;  // 128 threads
  __shared__ __align__(16) float arow[DDIM];
  for (int k = c; k < DDIM; k += 128) arow[k] = imgn[(size_t)m * DDIM + k];
  __syncthreads();
  const float4* br = (const float4*)(txtn + (size_t)c * DDIM);
  const float4* ar = (const float4*)arow;
  float dot = 0.f;
  #pragma unroll 8
  for (int k = 0; k < DDIM/4; ++k) {
    float4 x = ar[k], y = br[k];
    dot += x.x*y.x + x.y*y.y + x.z*y.z + x.w*y.w;
  }
  float t = expf(fminf(fmaxf(sc[0], -10.f), 10.f));
  float logit = fminf(fmaxf(t*dot + bi[0], -50.f), 50.f);
  float x = (c == m) ? logit : -logit;
  float v = neg_log_sigmoid(x);
  __shared__ float sb[2];
  #pragma unroll
  for (int o = 32; o; o >>= 1) v += __shfl_down(v, o);
  if ((c & 63) == 0) sb[c >> 6] = v;
  __syncthreads();
  if (c == 0) atomicAdd(acc, sb[0] + sb[1]);
}

__global__ void rc_loss_kernel(const float* __restrict__ Max, const int* __restrict__ counts,
                               const float* __restrict__ sc, const float* __restrict__ bi,
                               float* __restrict__ acc) {
  int m = blockIdx.x;
  int v = threadIdx.x;  // 128 threads
  const float* row = Max + (size_t)m * NCOLS + (size_t)v * WCON;
  int cnt = counts[v];
  float s = 0.f;
  for (int w = 0; w < cnt; ++w) s += row[w];
  float S = s / (float)cnt;
  float t = expf(fminf(fmaxf(sc[0], -10.f), 10.f));
  float logit = fminf(fmaxf(t*S + bi[0], -50.f), 50.f);
  float x = (v == m) ? logit : -logit;
  float val = neg_log_sigmoid(x);
  __shared__ float sb[2];
  #pragma unroll
  for (int o = 32; o; o >>= 1) val += __shfl_down(val, o);
  if ((v & 63) == 0) sb[v >> 6] = val;
  __syncthreads();
  if (v == 0) atomicAdd(acc, sb[0] + sb[1]);
}

__global__ void finalize_kernel(const float* __restrict__ acc, float* __restrict__ out) {
  if (threadIdx.x == 0 && blockIdx.x == 0) {
    float it = acc[0] * (1.f / 16384.f);
    float rc = acc[1] * (1.f / 16384.f);
    out[0] = it + 0.5f * rc;
    out[1] = it;
    out[2] = rc;
  }
}

// ---------------- launch ----------------

extern "C" void kernel_launch(void* const* d_in, const int* in_sizes, int n_in,
                              void* d_out, int out_size, void* d_ws, size_t ws_size,
                              hipStream_t stream) {
  const float* image_features        = (const float*)d_in[0];
  const float* text_features         = (const float*)d_in[1];
  const float* image_token_features  = (const float*)d_in[2];
  const float* concept_text_features = (const float*)d_in[3];
  const int*   concept_counts        = (const int*)d_in[4];
  const float* logit_scale           = (const float*)d_in[5];
  const float* logit_bias            = (const float*)d_in[6];
  float* out = (float*)d_out;

  if (ws_size < WS_NEED) {  // visible failure mode if workspace too small
    hipMemsetAsync(d_out, 0, (size_t)out_size * sizeof(float), stream);
    return;
  }

  char* ws = (char*)d_ws;
  ushort* patches  = (ushort*)(ws + P_OFF);
  ushort* concepts = (ushort*)(ws + C_OFF);
  float*  imgn     = (float*)(ws + IMGN_OFF);
  float*  txtn     = (float*)(ws + TXTN_OFF);
  float*  Maxbuf   = (float*)(ws + MAX_OFF);
  float*  acc      = (float*)(ws + ACC_OFF);

  hipMemsetAsync(acc, 0, 2 * sizeof(float), stream);

  norm_f32_kernel<<<BATCH, 192, 0, stream>>>(image_features, imgn);
  norm_f32_kernel<<<BATCH, 192, 0, stream>>>(text_features, txtn);
  norm_bf16_kernel<<<BATCH * NPAD, 192, 0, stream>>>(image_token_features, patches, NPATCH, NPAD);
  norm_bf16_kernel<<<NCOLS, 192, 0, stream>>>(concept_text_features, concepts, WCON, WCON);

  rc_gemm_max_kernel<<<BATCH * 32, 256, 0, stream>>>(patches, concepts, Maxbuf);

  it_loss_kernel<<<BATCH, 128, 0, stream>>>(imgn, txtn, logit_scale, logit_bias, acc);
  rc_loss_kernel<<<BATCH, 128, 0, stream>>>(Maxbuf, concept_counts, logit_scale, logit_bias, acc + 1);
  finalize_kernel<<<1, 64, 0, stream>>>(acc, out);
}